// Round 10
// baseline (145.121 us; speedup 1.0000x reference)
//
#include <hip/hip_runtime.h>

typedef _Float16 f16x8 __attribute__((ext_vector_type(8)));
typedef float f32x16 __attribute__((ext_vector_type(16)));

#define TRUNC_VAL 2.0f
#define WPB 4          // waves per block (chamfer)
#define TPSEG 16       // tiles per target segment
#define NBINS 4096     // 16^3 Morton bins
#define RANK_BITS 14
#define GRID_LO  -4.0f
#define GRID_INV  2.0f // 1 / 0.5 bin width

// ---------------------------------------------------------------------------
// R10: truncation-aware EXACT pruning. R8/R9 established the brute-force
// schedule's hard floor (~28.6us; chamfer ~22us vs 7us MFMA floor, all uarch
// knobs null). trunc=2.0 + Gaussian data means almost all 537M pairs are
// provably irrelevant. Plan: spatially sort both point sets (mean/min are
// permutation-invariant), bound tiles/segments with boxes, and skip any
// target tile with boxdist^2(Qbox,Tbox) >= ub, ub = wave-max of
// min(best_d2, trunc). Skip is exact: d2(i,j) >= LB >= ub >= min(best_i,
// trunc) can't change min(best_i, trunc). Per-pair math (frags, MFMA, fold)
// is byte-identical to the verified kernel. No device-scope fences (R2).
// ---------------------------------------------------------------------------

__device__ __forceinline__ unsigned mort4(unsigned v) {
    return (v & 1u) | ((v & 2u) << 2) | ((v & 4u) << 4) | ((v & 8u) << 6);
}

// set: 0 = p1 (fw targets), 1 = p0 (bw targets), 2 = p0+fw (fw queries),
//      3 = p0+fw-bw (bw queries)
__device__ __forceinline__ void load_point(int set, int i,
        const float* __restrict__ fw, const float* __restrict__ bw,
        const float* __restrict__ p0, const float* __restrict__ p1,
        float& x, float& y, float& z) {
    if (set == 0) { x = p1[3*i]; y = p1[3*i+1]; z = p1[3*i+2]; }
    else {
        x = p0[3*i]; y = p0[3*i+1]; z = p0[3*i+2];
        if (set >= 2) { x += fw[3*i]; y += fw[3*i+1]; z += fw[3*i+2]; }
        if (set == 3) { x -= bw[3*i]; y -= bw[3*i+1]; z -= bw[3*i+2]; }
    }
}

// --- S1: histogram + per-point (bin,rank); also zero the output scalar ----
__global__ void hist_kernel(const float* __restrict__ fw, const float* __restrict__ bw,
                            const float* __restrict__ p0, const float* __restrict__ p1,
                            int* __restrict__ hist, unsigned* __restrict__ aux,
                            float* __restrict__ out, int N) {
    int i = blockIdx.x * blockDim.x + threadIdx.x;
    int set = blockIdx.z;
    if (i == 0 && set == 0) out[0] = 0.0f;
    if (i >= N) return;
    float x, y, z; load_point(set, i, fw, bw, p0, p1, x, y, z);
    int xi = (int)((x - GRID_LO) * GRID_INV); xi = xi < 0 ? 0 : (xi > 15 ? 15 : xi);
    int yi = (int)((y - GRID_LO) * GRID_INV); yi = yi < 0 ? 0 : (yi > 15 ? 15 : yi);
    int zi = (int)((z - GRID_LO) * GRID_INV); zi = zi < 0 ? 0 : (zi > 15 ? 15 : zi);
    unsigned code = mort4(xi) | (mort4(yi) << 1) | (mort4(zi) << 2);   // < 4096
    int rank = atomicAdd(&hist[set * NBINS + code], 1);
    aux[(size_t)set * N + i] = (code << RANK_BITS) | (unsigned)rank;
}

// --- S2: exclusive scan of each set's 4096-bin histogram (1 block/set) ----
__global__ __launch_bounds__(1024) void scan_kernel(int* __restrict__ hist) {
    __shared__ int tmp[1024];
    int* h = hist + blockIdx.x * NBINS;
    int tid = threadIdx.x;
    int v[4], s = 0;
    #pragma unroll
    for (int k = 0; k < 4; ++k) { v[k] = h[tid * 4 + k]; s += v[k]; }
    tmp[tid] = s; __syncthreads();
    for (int off = 1; off < 1024; off <<= 1) {
        int x = (tid >= off) ? tmp[tid - off] : 0;
        __syncthreads();
        tmp[tid] += x;
        __syncthreads();
    }
    int excl = tmp[tid] - s;
    #pragma unroll
    for (int k = 0; k < 4; ++k) { int c = v[k]; h[tid * 4 + k] = excl; excl += c; }
}

// --- S3: scatter points into sorted float4 arrays (w = ||p||^2) -----------
__global__ void scatter_kernel(const float* __restrict__ fw, const float* __restrict__ bw,
                               const float* __restrict__ p0, const float* __restrict__ p1,
                               const int* __restrict__ hist, const unsigned* __restrict__ aux,
                               float4* __restrict__ S, int N) {
    int i = blockIdx.x * blockDim.x + threadIdx.x;
    int set = blockIdx.z;
    if (i >= N) return;
    unsigned av = aux[(size_t)set * N + i];
    unsigned code = av >> RANK_BITS;
    unsigned rank = av & ((1u << RANK_BITS) - 1u);
    int pos = hist[set * NBINS + code] + (int)rank;        // bijective
    float x, y, z; load_point(set, i, fw, bw, p0, p1, x, y, z);
    S[(size_t)set * N + pos] = make_float4(x, y, z, x*x + y*y + z*z);
}

// --- S4: A-panels (MFMA frags) + tile bounding boxes for both target sets -
// One 64-lane wave per tile. Fragment layout identical to the verified pack:
//   A: [xh yh zh | xh yh zh | xl yl zl | wh wl | 0...],  w = -0.5*||y||^2
__global__ __launch_bounds__(256) void panel_kernel(const float4* __restrict__ S,
        f16x8* __restrict__ Apanel, float4* __restrict__ TLo, float4* __restrict__ THi,
        int N, int nt) {
    int z = blockIdx.z;                       // target set 0/1
    int tile = blockIdx.x * 4 + (threadIdx.x >> 6);
    int lane = threadIdx.x & 63, r = lane & 31;
    bool hi = lane >= 32;
    float4 pt = S[(size_t)z * N + tile * 32 + r];
    float x = pt.x, y = pt.y, zc = pt.z;
    _Float16 xh = (_Float16)x, yh = (_Float16)y, zh = (_Float16)zc;
    _Float16 xl = (_Float16)(x  - (float)xh);
    _Float16 yl = (_Float16)(y  - (float)yh);
    _Float16 zl = (_Float16)(zc - (float)zh);
    float w = -0.5f * pt.w;
    _Float16 wh = (_Float16)w, wl = (_Float16)(w - (float)wh);
    f16x8 o;
    if (!hi) { o[0]=xh; o[1]=yh; o[2]=zh; o[3]=xh; o[4]=yh; o[5]=zh; o[6]=xl; o[7]=yl; }
    else {
        o[0]=zl; o[1]=wh; o[2]=wl;
        o[3]=(_Float16)0.0f; o[4]=(_Float16)0.0f; o[5]=(_Float16)0.0f;
        o[6]=(_Float16)0.0f; o[7]=(_Float16)0.0f;
    }
    Apanel[(size_t)z * nt * 64 + tile * 64 + lane] = o;
    float lx=x, ly=y, lz=zc, hx=x, hy=y, hz=zc;
    #pragma unroll
    for (int off = 1; off < 64; off <<= 1) {
        lx = fminf(lx, __shfl_xor(lx, off, 64));
        ly = fminf(ly, __shfl_xor(ly, off, 64));
        lz = fminf(lz, __shfl_xor(lz, off, 64));
        hx = fmaxf(hx, __shfl_xor(hx, off, 64));
        hy = fmaxf(hy, __shfl_xor(hy, off, 64));
        hz = fmaxf(hz, __shfl_xor(hz, off, 64));
    }
    if (lane == 0) {
        TLo[z * nt + tile] = make_float4(lx, ly, lz, 0.0f);
        THi[z * nt + tile] = make_float4(hx, hy, hz, 0.0f);
    }
}

// --- S5: segment bounding boxes (16 tiles each) ---------------------------
__global__ void segbox_kernel(const float4* __restrict__ TLo, const float4* __restrict__ THi,
                              float4* __restrict__ SLo, float4* __restrict__ SHi,
                              int nt, int nseg) {
    int z = blockIdx.z;
    int s = threadIdx.x;
    if (s >= nseg) return;
    float4 lo = TLo[z * nt + s * TPSEG], hb = THi[z * nt + s * TPSEG];
    float lx=lo.x, ly=lo.y, lz=lo.z, hx=hb.x, hy=hb.y, hz=hb.z;
    for (int k = 1; k < TPSEG; ++k) {
        float4 l2 = TLo[z * nt + s * TPSEG + k], h2 = THi[z * nt + s * TPSEG + k];
        lx = fminf(lx, l2.x); ly = fminf(ly, l2.y); lz = fminf(lz, l2.z);
        hx = fmaxf(hx, h2.x); hy = fmaxf(hy, h2.y); hz = fmaxf(hz, h2.z);
    }
    SLo[z * nseg + s] = make_float4(lx, ly, lz, 0.0f);
    SHi[z * nseg + s] = make_float4(hx, hy, hz, 0.0f);
}

// --- C: pruned chamfer. One wave = one 32-query tile vs ALL targets. ------
__global__ __launch_bounds__(256, 2) void chamfer_kernel(
        const f16x8* __restrict__ Apanel, const float4* __restrict__ S,
        const float4* __restrict__ TLo, const float4* __restrict__ THi,
        const float4* __restrict__ SLo, const float4* __restrict__ SHi,
        float* __restrict__ out, int N, float inv, int nt, int nseg) {
    int lane = threadIdx.x & 63, wave = threadIdx.x >> 6;
    int qt = blockIdx.x * WPB + wave;
    int z  = blockIdx.z;
    const f16x8*  Ap = Apanel + (size_t)z * nt * 64;
    const float4* Q  = S + (size_t)(2 + z) * N;
    float4 q4 = Q[qt * 32 + (lane & 31)];
    bool hi = lane >= 32;

    // B fragment (query layout, identical to verified pack)
    float qx = q4.x, qy = q4.y, qz = q4.z;
    _Float16 xh = (_Float16)qx, yh = (_Float16)qy, zh = (_Float16)qz;
    _Float16 xl = (_Float16)(qx - (float)xh);
    _Float16 yl = (_Float16)(qy - (float)yh);
    _Float16 zl = (_Float16)(qz - (float)zh);
    f16x8 b;
    if (!hi) { b[0]=xh; b[1]=yh; b[2]=zh; b[3]=xl; b[4]=yl; b[5]=zl; b[6]=xh; b[7]=yh; }
    else {
        b[0]=zh; b[1]=(_Float16)1.0f; b[2]=(_Float16)1.0f;
        b[3]=(_Float16)0.0f; b[4]=(_Float16)0.0f; b[5]=(_Float16)0.0f;
        b[6]=(_Float16)0.0f; b[7]=(_Float16)0.0f;
    }

    // wave query bounding box
    float qlx=qx, qly=qy, qlz=qz, qhx=qx, qhy=qy, qhz=qz;
    #pragma unroll
    for (int off = 1; off < 64; off <<= 1) {
        qlx = fminf(qlx, __shfl_xor(qlx, off, 64));
        qly = fminf(qly, __shfl_xor(qly, off, 64));
        qlz = fminf(qlz, __shfl_xor(qlz, off, 64));
        qhx = fmaxf(qhx, __shfl_xor(qhx, off, 64));
        qhy = fmaxf(qhy, __shfl_xor(qhy, off, 64));
        qhz = fmaxf(qhz, __shfl_xor(qhz, off, 64));
    }

    // per-lane segment lower bounds (lane s holds segment s)
    float slb = 3.0e38f;
    if (lane < nseg) {
        float4 lo = SLo[z * nseg + lane], hb = SHi[z * nseg + lane];
        float gx = fmaxf(0.0f, fmaxf(lo.x - qhx, qlx - hb.x));
        float gy = fmaxf(0.0f, fmaxf(lo.y - qhy, qly - hb.y));
        float gz = fmaxf(0.0f, fmaxf(lo.z - qhz, qlz - hb.z));
        slb = gx*gx + gy*gy + gz*gz;
    }
    // argmin segment (butterfly; deterministic tie-break)
    float mv_ = slb; int mi = lane;
    #pragma unroll
    for (int off = 1; off < 64; off <<= 1) {
        float ov = __shfl_xor(mv_, off, 64);
        int   oi = __shfl_xor(mi,  off, 64);
        if (ov < mv_ || (ov == mv_ && oi < mi)) { mv_ = ov; mi = oi; }
    }
    int s0 = mi;

    float m[4] = { -3.0e38f, -3.0e38f, -3.0e38f, -3.0e38f };
    const f32x16 zero = {};
    float ub = TRUNC_VAL;

    auto process_seg = [&](int s) {
        // per-lane tile LBs (lane t < 16 holds tile s*16+t)
        float lbt = 3.0e38f;
        int tb = s * TPSEG;
        if (lane < TPSEG) {
            float4 lo = TLo[z * nt + tb + lane], hb = THi[z * nt + tb + lane];
            float gx = fmaxf(0.0f, fmaxf(lo.x - qhx, qlx - hb.x));
            float gy = fmaxf(0.0f, fmaxf(lo.y - qhy, qly - hb.y));
            float gz = fmaxf(0.0f, fmaxf(lo.z - qhz, qlz - hb.z));
            lbt = gx*gx + gy*gy + gz*gz;
        }
        for (int t = 0; t < TPSEG; ++t) {
            float l = __shfl(lbt, t, 64);
            if (l < ub) {
                f16x8 a = Ap[(size_t)(tb + t) * 64 + lane];
                f32x16 d = __builtin_amdgcn_mfma_f32_32x32x16_f16(a, b, zero, 0, 0, 0);
                #pragma unroll
                for (int p = 0; p < 4; ++p) {
                    m[p] = fmaxf(fmaxf(m[p], d[4*p  ]), d[4*p+1]);
                    m[p] = fmaxf(fmaxf(m[p], d[4*p+2]), d[4*p+3]);
                }
            }
        }
    };
    auto update_ub = [&]() {
        float v = fmaxf(fmaxf(m[0], m[1]), fmaxf(m[2], m[3]));
        v = fmaxf(v, __shfl_xor(v, 32, 64));
        float d2 = fmaf(-2.0f, v, q4.w); d2 = fmaxf(d2, 0.0f);
        float dc = fminf(d2, TRUNC_VAL);
        float u = dc;
        #pragma unroll
        for (int off = 1; off < 64; off <<= 1) u = fmaxf(u, __shfl_xor(u, off, 64));
        ub = u;
    };

    process_seg(s0);           // nearest segment first -> tight ub
    update_ub();
    for (int s = 0; s < nseg; ++s) {
        if (s == s0) continue;
        float lb = __shfl(slb, s, 64);
        if (lb >= ub) continue;
        process_seg(s);
        update_ub();
    }

    // finalize: per-query truncated chamfer, block sum, one atomicAdd
    float v = fmaxf(fmaxf(m[0], m[1]), fmaxf(m[2], m[3]));
    v = fmaxf(v, __shfl_xor(v, 32, 64));
    float d2 = fmaf(-2.0f, v, q4.w); d2 = fmaxf(d2, 0.0f);
    float dc = fminf(d2, TRUNC_VAL);
    float cv = (lane < 32) ? dc : 0.0f;
    #pragma unroll
    for (int off = 1; off < 64; off <<= 1) cv += __shfl_xor(cv, off, 64);
    __shared__ float wsum[WPB];
    if (lane == 0) wsum[wave] = cv;
    __syncthreads();
    if (threadIdx.x == 0)
        atomicAdd(out, (wsum[0] + wsum[1] + wsum[2] + wsum[3]) * inv);
}

extern "C" void kernel_launch(void* const* d_in, const int* in_sizes, int n_in,
                              void* d_out, int out_size, void* d_ws, size_t ws_size,
                              hipStream_t stream) {
    const float* fw  = (const float*)d_in[0];
    const float* bwv = (const float*)d_in[1];
    const float* p0  = (const float*)d_in[2];
    const float* p1  = (const float*)d_in[3];
    int N = in_sizes[0] / 3;               // 16384
    int nt = N / 32;                       // 512 tiles
    int nseg = nt / TPSEG;                 // 32 segments

    float* out = (float*)d_out;
    char* w = (char*)d_ws;
    int*      hist = (int*)w;       w += (size_t)4 * NBINS * 4;
    unsigned* aux  = (unsigned*)w;  w += (size_t)4 * N * 4;
    float4*   S    = (float4*)w;    w += (size_t)4 * N * 16;
    f16x8* Apanel  = (f16x8*)w;     w += (size_t)2 * nt * 64 * 16;
    float4*   TLo  = (float4*)w;    w += (size_t)2 * nt * 16;
    float4*   THi  = (float4*)w;    w += (size_t)2 * nt * 16;
    float4*   SLo  = (float4*)w;    w += (size_t)2 * nseg * 16;
    float4*   SHi  = (float4*)w;

    hipMemsetAsync(hist, 0, (size_t)4 * NBINS * 4, stream);
    dim3 gp((N + 255) / 256, 1, 4);
    hist_kernel<<<gp, 256, 0, stream>>>(fw, bwv, p0, p1, hist, aux, out, N);
    scan_kernel<<<4, 1024, 0, stream>>>(hist);
    scatter_kernel<<<gp, 256, 0, stream>>>(fw, bwv, p0, p1, hist, aux, S, N);
    panel_kernel<<<dim3(nt / 4, 1, 2), 256, 0, stream>>>(S, Apanel, TLo, THi, N, nt);
    segbox_kernel<<<dim3(1, 1, 2), 64, 0, stream>>>(TLo, THi, SLo, SHi, nt, nseg);
    chamfer_kernel<<<dim3((N / 32) / WPB, 1, 2), 256, 0, stream>>>(
        Apanel, S, TLo, THi, SLo, SHi, out, N, 1.0f / N, nt, nseg);
}

// Round 11
// 51.860 us; speedup vs baseline: 2.7984x; 2.7984x over previous
//
#include <hip/hip_runtime.h>

typedef _Float16 f16x8 __attribute__((ext_vector_type(8)));
typedef float f32x16 __attribute__((ext_vector_type(16)));

#define TRUNC_VAL 2.0f
#define NBINS 4096     // 16^3 Morton bins
#define RANK_BITS 14
#define GRID_LO  -4.0f
#define GRID_INV  2.0f
#define CW 8           // chamfer waves per block

// ---------------------------------------------------------------------------
// R11: R10's exact pruning (validated, absmax 0.0, 76% MFMA kill) with the
// parallelism fixed. R10's chamfer was 121us at 1 wave/SIMD (Occ 5.9%) —
// pure latency exposure. New shape: 1 block per (query tile, dir), 8 waves;
// each lane owns ONE target tile's box LB (512 tiles = 64 lanes x 8 waves);
// phase 1 = every wave processes its local-nearest segment dense (ILP-2,
// prefetch); LDS-combine -> tight shared ub; phase 2 = ballot-masked sweep
// of surviving tiles. Segment boxes and the reduce kernel are deleted
// (min-over-tile-LB is tighter; block finishes its 32 queries itself).
// Skip exactness: d2(i,t) >= LB >= ub >= clamp(final_i) can't change
// min(best_i, trunc). No device-scope fences (R2 lesson).
// ---------------------------------------------------------------------------

__device__ __forceinline__ unsigned mort4(unsigned v) {
    return (v & 1u) | ((v & 2u) << 2) | ((v & 4u) << 4) | ((v & 8u) << 6);
}

// set: 0 = p1 (fw targets), 1 = p0 (bw targets), 2 = p0+fw (fw queries),
//      3 = p0+fw-bw (bw queries)
__device__ __forceinline__ void load_point(int set, int i,
        const float* __restrict__ fw, const float* __restrict__ bw,
        const float* __restrict__ p0, const float* __restrict__ p1,
        float& x, float& y, float& z) {
    if (set == 0) { x = p1[3*i]; y = p1[3*i+1]; z = p1[3*i+2]; }
    else {
        x = p0[3*i]; y = p0[3*i+1]; z = p0[3*i+2];
        if (set >= 2) { x += fw[3*i]; y += fw[3*i+1]; z += fw[3*i+2]; }
        if (set == 3) { x -= bw[3*i]; y -= bw[3*i+1]; z -= bw[3*i+2]; }
    }
}

// --- S1: histogram + per-point (bin,rank); also zero the output scalar ----
__global__ void hist_kernel(const float* __restrict__ fw, const float* __restrict__ bw,
                            const float* __restrict__ p0, const float* __restrict__ p1,
                            int* __restrict__ hist, unsigned* __restrict__ aux,
                            float* __restrict__ out, int N) {
    int i = blockIdx.x * blockDim.x + threadIdx.x;
    int set = blockIdx.z;
    if (i == 0 && set == 0) out[0] = 0.0f;
    if (i >= N) return;
    float x, y, z; load_point(set, i, fw, bw, p0, p1, x, y, z);
    int xi = (int)((x - GRID_LO) * GRID_INV); xi = xi < 0 ? 0 : (xi > 15 ? 15 : xi);
    int yi = (int)((y - GRID_LO) * GRID_INV); yi = yi < 0 ? 0 : (yi > 15 ? 15 : yi);
    int zi = (int)((z - GRID_LO) * GRID_INV); zi = zi < 0 ? 0 : (zi > 15 ? 15 : zi);
    unsigned code = mort4(xi) | (mort4(yi) << 1) | (mort4(zi) << 2);   // < 4096
    int rank = atomicAdd(&hist[set * NBINS + code], 1);
    aux[(size_t)set * N + i] = (code << RANK_BITS) | (unsigned)rank;
}

// --- S2: exclusive scan of each set's 4096-bin histogram (1 block/set) ----
__global__ __launch_bounds__(1024) void scan_kernel(int* __restrict__ hist) {
    __shared__ int tmp[1024];
    int* h = hist + blockIdx.x * NBINS;
    int tid = threadIdx.x;
    int v[4], s = 0;
    #pragma unroll
    for (int k = 0; k < 4; ++k) { v[k] = h[tid * 4 + k]; s += v[k]; }
    tmp[tid] = s; __syncthreads();
    for (int off = 1; off < 1024; off <<= 1) {
        int x = (tid >= off) ? tmp[tid - off] : 0;
        __syncthreads();
        tmp[tid] += x;
        __syncthreads();
    }
    int excl = tmp[tid] - s;
    #pragma unroll
    for (int k = 0; k < 4; ++k) { int c = v[k]; h[tid * 4 + k] = excl; excl += c; }
}

// --- S3: scatter points into sorted float4 arrays (w = ||p||^2) -----------
__global__ void scatter_kernel(const float* __restrict__ fw, const float* __restrict__ bw,
                               const float* __restrict__ p0, const float* __restrict__ p1,
                               const int* __restrict__ hist, const unsigned* __restrict__ aux,
                               float4* __restrict__ S, int N) {
    int i = blockIdx.x * blockDim.x + threadIdx.x;
    int set = blockIdx.z;
    if (i >= N) return;
    unsigned av = aux[(size_t)set * N + i];
    unsigned code = av >> RANK_BITS;
    unsigned rank = av & ((1u << RANK_BITS) - 1u);
    int pos = hist[set * NBINS + code] + (int)rank;        // bijective
    float x, y, z; load_point(set, i, fw, bw, p0, p1, x, y, z);
    S[(size_t)set * N + pos] = make_float4(x, y, z, x*x + y*y + z*z);
}

// --- S4: A-panels (MFMA frags) + tile bounding boxes for target sets ------
__global__ __launch_bounds__(256) void panel_kernel(const float4* __restrict__ S,
        f16x8* __restrict__ Apanel, float4* __restrict__ TLo, float4* __restrict__ THi,
        int N, int nt) {
    int z = blockIdx.z;                       // target set 0/1
    int tile = blockIdx.x * 4 + (threadIdx.x >> 6);
    int lane = threadIdx.x & 63, r = lane & 31;
    bool hi = lane >= 32;
    float4 pt = S[(size_t)z * N + tile * 32 + r];
    float x = pt.x, y = pt.y, zc = pt.z;
    _Float16 xh = (_Float16)x, yh = (_Float16)y, zh = (_Float16)zc;
    _Float16 xl = (_Float16)(x  - (float)xh);
    _Float16 yl = (_Float16)(y  - (float)yh);
    _Float16 zl = (_Float16)(zc - (float)zh);
    float w = -0.5f * pt.w;
    _Float16 wh = (_Float16)w, wl = (_Float16)(w - (float)wh);
    f16x8 o;
    if (!hi) { o[0]=xh; o[1]=yh; o[2]=zh; o[3]=xh; o[4]=yh; o[5]=zh; o[6]=xl; o[7]=yl; }
    else {
        o[0]=zl; o[1]=wh; o[2]=wl;
        o[3]=(_Float16)0.0f; o[4]=(_Float16)0.0f; o[5]=(_Float16)0.0f;
        o[6]=(_Float16)0.0f; o[7]=(_Float16)0.0f;
    }
    Apanel[(size_t)z * nt * 64 + tile * 64 + lane] = o;
    float lx=x, ly=y, lz=zc, hx=x, hy=y, hz=zc;
    #pragma unroll
    for (int off = 1; off < 64; off <<= 1) {
        lx = fminf(lx, __shfl_xor(lx, off, 64));
        ly = fminf(ly, __shfl_xor(ly, off, 64));
        lz = fminf(lz, __shfl_xor(lz, off, 64));
        hx = fmaxf(hx, __shfl_xor(hx, off, 64));
        hy = fmaxf(hy, __shfl_xor(hy, off, 64));
        hz = fmaxf(hz, __shfl_xor(hz, off, 64));
    }
    if (lane == 0) {
        TLo[z * nt + tile] = make_float4(lx, ly, lz, 0.0f);
        THi[z * nt + tile] = make_float4(hx, hy, hz, 0.0f);
    }
}

#define FOLD(d)                                                     \
    _Pragma("unroll")                                               \
    for (int p = 0; p < 4; ++p) {                                   \
        m[p] = fmaxf(fmaxf(m[p], d[4*p  ]), d[4*p+1]);              \
        m[p] = fmaxf(fmaxf(m[p], d[4*p+2]), d[4*p+3]);              \
    }

// --- C: fused pruned chamfer. One block = one (query tile, dir). ----------
__global__ __launch_bounds__(64 * CW, 4) void chamfer_fused(
        const f16x8* __restrict__ Apanel, const float4* __restrict__ S,
        const float4* __restrict__ TLo, const float4* __restrict__ THi,
        float* __restrict__ out, int N, float inv, int nt) {
    __shared__ float sM[CW][32];
    int tid = threadIdx.x;
    int lane = tid & 63, w = tid >> 6;
    int qt = blockIdx.x, z = blockIdx.z;
    int r = lane & 31; bool hi = lane >= 32;
    const f16x8* Ap = Apanel + (size_t)z * nt * 64;

    float4 q4 = S[(size_t)(2 + z) * N + qt * 32 + r];

    // B fragment (identical layout to the verified pack)
    float qx = q4.x, qy = q4.y, qz = q4.z;
    _Float16 xh = (_Float16)qx, yh = (_Float16)qy, zh = (_Float16)qz;
    _Float16 xl = (_Float16)(qx - (float)xh);
    _Float16 yl = (_Float16)(qy - (float)yh);
    _Float16 zl = (_Float16)(qz - (float)zh);
    f16x8 b;
    if (!hi) { b[0]=xh; b[1]=yh; b[2]=zh; b[3]=xl; b[4]=yl; b[5]=zl; b[6]=xh; b[7]=yh; }
    else {
        b[0]=zh; b[1]=(_Float16)1.0f; b[2]=(_Float16)1.0f;
        b[3]=(_Float16)0.0f; b[4]=(_Float16)0.0f; b[5]=(_Float16)0.0f;
        b[6]=(_Float16)0.0f; b[7]=(_Float16)0.0f;
    }

    // query-tile bounding box (same in every wave)
    float qlx=qx, qly=qy, qlz=qz, qhx=qx, qhy=qy, qhz=qz;
    #pragma unroll
    for (int off = 1; off < 64; off <<= 1) {
        qlx = fminf(qlx, __shfl_xor(qlx, off, 64));
        qly = fminf(qly, __shfl_xor(qly, off, 64));
        qlz = fminf(qlz, __shfl_xor(qlz, off, 64));
        qhx = fmaxf(qhx, __shfl_xor(qhx, off, 64));
        qhy = fmaxf(qhy, __shfl_xor(qhy, off, 64));
        qhz = fmaxf(qhz, __shfl_xor(qhz, off, 64));
    }

    // per-lane tile LB: lane owns tile (w + 8*(lane>>4))*16 + (lane&15)
    int g    = lane >> 4;                    // group 0..3 -> segment w + 8g
    int tile = (w + CW * g) * 16 + (lane & 15);
    float4 lo = TLo[z * nt + tile], hb = THi[z * nt + tile];
    float gx = fmaxf(0.0f, fmaxf(lo.x - qhx, qlx - hb.x));
    float gy = fmaxf(0.0f, fmaxf(lo.y - qhy, qly - hb.y));
    float gz = fmaxf(0.0f, fmaxf(lo.z - qhz, qlz - hb.z));
    float lb = gx*gx + gy*gy + gz*gz;

    // per-segment min LB (within each 16-lane group)
    float slb = lb;
    #pragma unroll
    for (int off = 1; off < 16; off <<= 1) slb = fminf(slb, __shfl_xor(slb, off, 64));
    // wave-local nearest group (butterfly over lane bits 4..5)
    float s0v = slb; int s0g = g;
    #pragma unroll
    for (int off = 16; off < 64; off <<= 1) {
        float ov = __shfl_xor(s0v, off, 64);
        int   og = __shfl_xor(s0g, off, 64);
        if (ov < s0v || (ov == s0v && og < s0g)) { s0v = ov; s0g = og; }
    }

    float m[4] = { -3.0e38f, -3.0e38f, -3.0e38f, -3.0e38f };
    const f32x16 zero = {};

    // ---- phase 1: dense sweep of the wave's nearest segment (ILP-2) ----
    int tb0 = (w + CW * s0g) * 16;
    f16x8 a0 = Ap[(size_t)(tb0    ) * 64 + lane];
    f16x8 a1 = Ap[(size_t)(tb0 + 1) * 64 + lane];
    for (int t = 0; t < 16; t += 2) {
        f16x8 c0 = a0, c1 = a1;
        int t2 = (t + 2 < 16) ? t + 2 : t;
        int t3 = (t + 3 < 16) ? t + 3 : t + 1;
        a0 = Ap[(size_t)(tb0 + t2) * 64 + lane];
        a1 = Ap[(size_t)(tb0 + t3) * 64 + lane];
        f32x16 d0 = __builtin_amdgcn_mfma_f32_32x32x16_f16(c0, b, zero, 0, 0, 0);
        f32x16 d1 = __builtin_amdgcn_mfma_f32_32x32x16_f16(c1, b, zero, 0, 0, 0);
        FOLD(d0) FOLD(d1)
    }

    // ---- combine -> shared ub ----
    float v = fmaxf(fmaxf(m[0], m[1]), fmaxf(m[2], m[3]));
    v = fmaxf(v, __shfl_xor(v, 32, 64));
    if (lane < 32) sM[w][lane] = v;
    __syncthreads();
    float mx = sM[0][r];
    #pragma unroll
    for (int ww = 1; ww < CW; ++ww) mx = fmaxf(mx, sM[ww][r]);
    float d2c = fmaf(-2.0f, mx, q4.w);
    d2c = fmaxf(d2c, 0.0f); d2c = fminf(d2c, TRUNC_VAL);
    float ub = d2c;
    #pragma unroll
    for (int off = 1; off < 64; off <<= 1) ub = fmaxf(ub, __shfl_xor(ub, off, 64));
    __syncthreads();                          // sM reads done before reuse

    // ---- phase 2: ballot-masked sweep of surviving tiles ----
    unsigned long long bal = __ballot(lb < ub);
    #pragma unroll
    for (int k = 0; k < 4; ++k) {
        if (k == s0g) continue;
        float sgm = __shfl(slb, k << 4, 64);
        if (sgm >= ub) continue;
        unsigned msk = (unsigned)((bal >> (16 * k)) & 0xFFFFull);
        int tb = (w + CW * k) * 16;
        while (msk) {
            int t = __builtin_ctz(msk); msk &= msk - 1;
            f16x8 a = Ap[(size_t)(tb + t) * 64 + lane];
            f32x16 d = __builtin_amdgcn_mfma_f32_32x32x16_f16(a, b, zero, 0, 0, 0);
            FOLD(d)
        }
    }

    // ---- final combine, truncated chamfer, block sum, one atomicAdd ----
    v = fmaxf(fmaxf(m[0], m[1]), fmaxf(m[2], m[3]));
    v = fmaxf(v, __shfl_xor(v, 32, 64));
    if (lane < 32) sM[w][lane] = v;
    __syncthreads();
    if (w == 0) {
        float mx2 = sM[0][r];
        #pragma unroll
        for (int ww = 1; ww < CW; ++ww) mx2 = fmaxf(mx2, sM[ww][r]);
        float d2 = fmaf(-2.0f, mx2, q4.w);
        d2 = fmaxf(d2, 0.0f);
        float dc = fminf(d2, TRUNC_VAL);
        float c = (lane < 32) ? dc : 0.0f;
        #pragma unroll
        for (int off = 1; off < 64; off <<= 1) c += __shfl_xor(c, off, 64);
        if (lane == 0) atomicAdd(out, c * inv);
    }
}
#undef FOLD

extern "C" void kernel_launch(void* const* d_in, const int* in_sizes, int n_in,
                              void* d_out, int out_size, void* d_ws, size_t ws_size,
                              hipStream_t stream) {
    const float* fw  = (const float*)d_in[0];
    const float* bwv = (const float*)d_in[1];
    const float* p0  = (const float*)d_in[2];
    const float* p1  = (const float*)d_in[3];
    int N = in_sizes[0] / 3;               // 16384
    int nt = N / 32;                       // 512 tiles

    float* out = (float*)d_out;
    char* w = (char*)d_ws;
    int*      hist = (int*)w;       w += (size_t)4 * NBINS * 4;
    unsigned* aux  = (unsigned*)w;  w += (size_t)4 * N * 4;
    float4*   S    = (float4*)w;    w += (size_t)4 * N * 16;
    f16x8* Apanel  = (f16x8*)w;     w += (size_t)2 * nt * 64 * 16;
    float4*   TLo  = (float4*)w;    w += (size_t)2 * nt * 16;
    float4*   THi  = (float4*)w;

    hipMemsetAsync(hist, 0, (size_t)4 * NBINS * 4, stream);
    dim3 gp((N + 255) / 256, 1, 4);
    hist_kernel<<<gp, 256, 0, stream>>>(fw, bwv, p0, p1, hist, aux, out, N);
    scan_kernel<<<4, 1024, 0, stream>>>(hist);
    scatter_kernel<<<gp, 256, 0, stream>>>(fw, bwv, p0, p1, hist, aux, S, N);
    panel_kernel<<<dim3(nt / 4, 1, 2), 256, 0, stream>>>(S, Apanel, TLo, THi, N, nt);
    chamfer_fused<<<dim3(nt, 1, 2), 64 * CW, 0, stream>>>(
        Apanel, S, TLo, THi, out, N, 1.0f / N, nt);
}